// Round 11
// baseline (268.974 us; speedup 1.0000x reference)
//
#include <hip/hip_runtime.h>
#include <math.h>

typedef __attribute__((ext_vector_type(8))) short short8;
typedef __attribute__((ext_vector_type(4))) float f32x4;
typedef __attribute__((ext_vector_type(2))) unsigned int u32x2;

#define AS1 __attribute__((address_space(1)))
#define AS3 __attribute__((address_space(3)))

__device__ __forceinline__ float b2f(short s){
  return __uint_as_float(((unsigned int)(unsigned short)s) << 16);
}
__device__ __forceinline__ short f2b(float f){
  unsigned int u = __float_as_uint(f);
  u = (u + 0x7fffu + ((u >> 16) & 1u)) >> 16;
  return (short)u;
}
__device__ __forceinline__ unsigned pk2(float lo, float hi){
  return ((unsigned)(unsigned short)f2b(hi) << 16) | (unsigned)(unsigned short)f2b(lo);
}

// ---------------- weight f32 -> bf16, linear stage-order [s][row][g][8] ------
__global__ __launch_bounds__(256) void cvt_w(
    const float* __restrict__ s0, const float* __restrict__ s1,
    const float* __restrict__ s2, const float* __restrict__ s3,
    const float* __restrict__ s4, const float* __restrict__ s5,
    short* __restrict__ dst)
{
  const float* srcs[6] = {s0, s1, s2, s3, s4, s5};
  int i = blockIdx.x * 256 + threadIdx.x;       // 6*65536 total
  int mat = i >> 16, rc = i & 65535;
  int row = rc >> 8, col = rc & 255;
  int d = mat * 65536 + ((col >> 5) << 13) + (row << 5)
        + (((col >> 3) & 3) << 3) + (col & 7);
  dst[d] = f2b(srcs[mat][rc]);
}

// ---------------- LayerNorm f32 -> bf16 afrag writer -------------------------
// Block = 1 tile (64 rows), 256 thr (4 thr/row, 64 cols each).
// afrag: chunk (tile,s,w,lane=g*16+l15) = row w*16+l15, cols s*32+g*8 (16B).
__global__ __launch_bounds__(256) void lnq_k(
    const float* __restrict__ x, const float* __restrict__ g,
    const float* __restrict__ bta, short* __restrict__ af)
{
  const int tile = blockIdx.x, tid = threadIdx.x;
  const int row = tid >> 2, c0 = (tid & 3) << 6;
  const float* src = &x[((size_t)tile * 64 + row) * 256 + c0];
  float vv[64];
  #pragma unroll
  for (int i = 0; i < 16; ++i) *(f32x4*)&vv[4 * i] = *(const f32x4*)&src[4 * i];
  float s1 = 0.f, s2 = 0.f;
  #pragma unroll
  for (int i = 0; i < 64; ++i){ s1 += vv[i]; s2 += vv[i] * vv[i]; }
  s1 += __shfl_xor(s1, 1); s2 += __shfl_xor(s2, 1);
  s1 += __shfl_xor(s1, 2); s2 += __shfl_xor(s2, 2);
  const float mu = s1 * 0.00390625f;
  const float rs = rsqrtf(s2 * 0.00390625f - mu * mu + 1e-5f);
  const int w = row >> 4, l15 = row & 15;
  #pragma unroll
  for (int i = 0; i < 8; ++i){
    const int col0 = c0 + 8 * i;
    f32x4 g0 = *(const f32x4*)&g[col0],   g1 = *(const f32x4*)&g[col0 + 4];
    f32x4 b0 = *(const f32x4*)&bta[col0], b1 = *(const f32x4*)&bta[col0 + 4];
    short8 o;
    #pragma unroll
    for (int j = 0; j < 4; ++j) o[j] = f2b((vv[8 * i + j] - mu) * rs * g0[j] + b0[j]);
    #pragma unroll
    for (int j = 0; j < 4; ++j) o[4 + j] = f2b((vv[8 * i + 4 + j] - mu) * rs * g1[j] + b1[j]);
    const int s = col0 >> 5, gg = (col0 >> 3) & 3;
    *(short8*)&af[((((size_t)tile * 8 + s) * 4 + w) * 64 + gg * 16 + l15) * 8] = o;
  }
}

// ---------------- barrier-free streaming GEMM: C[M,256] = A @ W^T + b --------
// W (128KB, stage-order) resident in LDS (staged once, 1 barrier). A read
// directly from global in afrag layout (coalesced 1KB/wave-instr), prefetched
// one tile ahead. Grid-strides over 64-row tiles. No barriers in the loop.
// Epilogue: GELU / RES=1 row-major f32 residual / OF row-major f32 out /
//           OT: 1 kfrag, 2 vfrag, 4 afrag-bf16 / LNO: row-LN -> afrag outL.
template<int GELU, int RES, int OF, int OT, int LNO>
__global__ __launch_bounds__(256, 1) void gemmF(
    const short* __restrict__ Aaf, const short* __restrict__ Wst,
    const float* __restrict__ bias, const float* __restrict__ resF,
    float* __restrict__ outF, short* __restrict__ outB,
    const float* __restrict__ lng, const float* __restrict__ lnb,
    short* __restrict__ outL, int ntiles)
{
  extern __shared__ __align__(16) short Wl[];   // 65536 shorts = 128KB
  const int tid = threadIdx.x;
  const int w = tid >> 6, lane = tid & 63;
  const int l15 = lane & 15, g = lane >> 4;

  // ---- stage all of W once (async, coalesced) ----
  #pragma unroll
  for (int it = 0; it < 32; ++it){
    int c = (it << 8) + tid;
    __builtin_amdgcn_global_load_lds((const AS1 void*)(Wst + ((size_t)c << 3)),
                                     (AS3 void*)(Wl + (c << 3)), 16, 0, 0);
  }

  int tile = blockIdx.x;
  short8 afN[8];
  #pragma unroll
  for (int s = 0; s < 8; ++s)
    afN[s] = *(const short8*)&Aaf[((((size_t)tile << 3) + s) * 4 + w) * 512 + (lane << 3)];
  __syncthreads();                               // W (and first A) ready

  while (tile < ntiles){
    short8 afC[8];
    #pragma unroll
    for (int s = 0; s < 8; ++s) afC[s] = afN[s];
    const int nxt = tile + (int)gridDim.x;
    if (nxt < ntiles){
      #pragma unroll
      for (int s = 0; s < 8; ++s)
        afN[s] = *(const short8*)&Aaf[((((size_t)nxt << 3) + s) * 4 + w) * 512 + (lane << 3)];
    }

    f32x4 acc[16];
    #pragma unroll
    for (int nt = 0; nt < 16; ++nt) acc[nt] = {0.f, 0.f, 0.f, 0.f};
    #pragma unroll
    for (int s = 0; s < 8; ++s){
      const short8 af = afC[s];
      #pragma unroll
      for (int nt = 0; nt < 16; ++nt){
        short8 bf = *(const short8*)&Wl[(s << 13) + ((nt << 4) + l15) * 32 + (g << 3)];
        acc[nt] = __builtin_amdgcn_mfma_f32_16x16x32_bf16(af, bf, acc[nt], 0, 0, 0);
      }
    }

    // ---- epilogue ----
    const int m0 = tile << 6;
    const int row_l = (w << 4) + (g << 2);
    #pragma unroll
    for (int nt = 0; nt < 16; ++nt){
      const int col = (nt << 4) + l15;
      const float bv = bias[col];
      #pragma unroll
      for (int r = 0; r < 4; ++r){
        const int m = m0 + row_l + r;
        const size_t idx = (size_t)m * 256 + col;
        float v = acc[nt][r] + bv;
        if (GELU) v = 0.5f * v * (1.0f + erff(v * 0.70710678118f));
        if (RES) v += resF[idx];
        if (OF) outF[idx] = v;
        acc[nt][r] = v;
        if (OT == 1){   // kfrag: [b][h][nt16][half][g][l15][8]
          const int b_ = m >> 8, kvr = m & 255;
          const int knt = kvr >> 4, kl = kvr & 15;
          const int h = col >> 6, half = (col >> 5) & 1, kg = (col >> 3) & 3, kj = col & 7;
          outB[(((((size_t)(b_ * 4 + h) * 16 + knt) * 2 + half) * 4 + kg) * 16 + kl) * 8 + kj] = f2b(v);
        }
        if (OT == 2){   // vfrag: [b][h][kk][n2][g][l15][8]
          const int b_ = m >> 8, kvj = m & 255;
          const int jp = (kvj & ~31) | (((kvj >> 2) & 3) << 3) | (((kvj >> 4) & 1) << 2) | (kvj & 3);
          const int h = col >> 6, dp = col & 63;
          const int kk = jp >> 5, vg = (jp >> 3) & 3, vj = jp & 7;
          const int vn2 = dp >> 4, vl = dp & 15;
          outB[(((((size_t)(b_ * 4 + h) * 8 + kk) * 4 + vn2) * 4 + vg) * 16 + vl) * 8 + vj] = f2b(v);
        }
        if (OT == 4){   // standard afrag
          outB[((((size_t)tile * 8 + (col >> 5)) * 4 + w) * 64
                + (((col >> 3) & 3) << 4) + (g << 2) + r) * 8 + (col & 7)] = f2b(v);
        }
      }
    }
    if (LNO){
      #pragma unroll
      for (int r = 0; r < 4; ++r){
        float s1 = 0.f, s2 = 0.f;
        #pragma unroll
        for (int nt = 0; nt < 16; ++nt){ float v = acc[nt][r]; s1 += v; s2 += v * v; }
        #pragma unroll
        for (int off = 1; off < 16; off <<= 1){ s1 += __shfl_xor(s1, off); s2 += __shfl_xor(s2, off); }
        const float mu = s1 * 0.00390625f;
        const float rs = rsqrtf(s2 * 0.00390625f - mu * mu + 1e-5f);
        #pragma unroll
        for (int nt = 0; nt < 16; ++nt){
          const int col = (nt << 4) + l15;
          float lv = (acc[nt][r] - mu) * rs * lng[col] + lnb[col];
          outL[((((size_t)tile * 8 + (col >> 5)) * 4 + w) * 64
                + (((col >> 3) & 3) << 4) + (g << 2) + r) * 8 + (col & 7)] = f2b(lv);
        }
      }
    }
    tile = nxt;
  }
}

// ---------------- fused MFMA attention (r10 structure) ----------------
// Block: 256 thr = 4 waves x 16 q-rows; grid 64x8 = 512 blocks (2/CU).
// LDS 64KB: K | V split-phase staging. cw: 1KB bursts -> swizzled LDS bounce
// -> packed regs. Q from standard afrag. ctx written in afrag order for O.
// am via LDS bounce -> 1KB-burst stores.
__global__ __launch_bounds__(256, 2) void attn_k(
    const short* __restrict__ Qf, const short* __restrict__ Kf,
    const short* __restrict__ Vf, const float* __restrict__ cw,
    short* __restrict__ ctx, float* __restrict__ am_out)
{
  extern __shared__ __align__(16) short smem[];   // 32768 shorts = 64KB
  short* Kl = smem;
  short* Vl = smem + 16384;
  const int b = blockIdx.y;
  const int q0 = blockIdx.x << 6;
  const int tid = threadIdx.x;
  const int w = tid >> 6, lane = tid & 63;
  const int l15 = lane & 15, g = lane >> 4;
  const size_t qw = (size_t)b * 4096 + q0 + (w << 4);   // wave's first q row
  const size_t qblk = qw >> 4;
  const size_t tileQ = qblk >> 2;
  const int wQ = (int)(qblk & 3);
  const size_t tileC = (size_t)b * 64 + blockIdx.x;     // ctx afrag tile

#define STG(dst_, src_) do{ _Pragma("unroll")                                        \
  for (int it_ = 0; it_ < 8; ++it_){ int c_ = (it_ << 8) + tid;                      \
    __builtin_amdgcn_global_load_lds((const AS1 void*)((src_) + (c_ << 3)),          \
                                     (AS3 void*)((dst_) + (c_ << 3)), 16, 0, 0); } }while(0)

  // ---- cw: full-row coalesced load -> swizzled LDS -> scattered reg read ----
  unsigned cwp[16][2];
  f32x4 am[16];
  {
    char* reg = (char*)smem + (w << 13);       // 8KB per wave
    #pragma unroll
    for (int j = 0; j < 16; ++j){
      f32x4 v = *(const f32x4*)&cw[(qw + j) * 256 + (lane << 2)];  // 1KB burst/instr
      u32x2 d = { pk2(v[0], v[1]), pk2(v[2], v[3]) };
      unsigned off = ((j << 9) + (lane << 3)) ^ ((j & 7) << 4);
      *(u32x2*)(reg + off) = d;
    }
    __syncthreads();
    #pragma unroll
    for (int nt = 0; nt < 16; ++nt){
      unsigned base = ((l15 << 9) + (nt << 5) + (g << 3)) ^ ((l15 & 7) << 4);
      cwp[nt][0] = *(const unsigned*)(reg + base);
      cwp[nt][1] = *(const unsigned*)(reg + base + 4);
      am[nt] = {0.f, 0.f, 0.f, 0.f};
    }
    __syncthreads();
  }

  STG(Kl, Kf + ((size_t)(b * 4) << 14));
  __syncthreads();                       // K(0) staged

  for (int h = 0; h < 4; ++h){
    STG(Vl, Vf + ((size_t)(b * 4 + h) << 14));          // V(h) under QK
    short8 qf0 = *(const short8*)&Qf[(((tileQ * 8 + (h << 1)) * 4 + wQ) * 64 + lane) * 8];
    short8 qf1 = *(const short8*)&Qf[(((tileQ * 8 + (h << 1) + 1) * 4 + wQ) * 64 + lane) * 8];

    // ---- scores: swapped operands, lane-contiguous ds_read_b128 ----
    f32x4 acc[16];
    #pragma unroll
    for (int nt = 0; nt < 16; ++nt) acc[nt] = {0.f, 0.f, 0.f, 0.f};
    #pragma unroll
    for (int nt = 0; nt < 16; ++nt){
      short8 kf0 = *(const short8*)&Kl[(nt << 10) + (lane << 3)];
      acc[nt] = __builtin_amdgcn_mfma_f32_16x16x32_bf16(kf0, qf0, acc[nt], 0, 0, 0);
      short8 kf1 = *(const short8*)&Kl[(nt << 10) + 512 + (lane << 3)];
      acc[nt] = __builtin_amdgcn_mfma_f32_16x16x32_bf16(kf1, qf1, acc[nt], 0, 0, 0);
    }
    __syncthreads();                     // V(h) ready; all waves done with Kl
    if (h < 3) STG(Kl, Kf + ((size_t)(b * 4 + h + 1) << 14));   // K(h+1) under softmax+PV

    // ---- softmax, fully in-lane (row q = l15; partners at lane^16, lane^32) ----
    float mx = -3.4e38f;
    #pragma unroll
    for (int nt = 0; nt < 16; ++nt){
      float c0 = __uint_as_float(cwp[nt][0] << 16);
      float c1 = __uint_as_float(cwp[nt][0] & 0xffff0000u);
      float c2 = __uint_as_float(cwp[nt][1] << 16);
      float c3 = __uint_as_float(cwp[nt][1] & 0xffff0000u);
      acc[nt][0] = acc[nt][0] * 0.125f + c0;
      acc[nt][1] = acc[nt][1] * 0.125f + c1;
      acc[nt][2] = acc[nt][2] * 0.125f + c2;
      acc[nt][3] = acc[nt][3] * 0.125f + c3;
      mx = fmaxf(mx, fmaxf(fmaxf(acc[nt][0], acc[nt][1]), fmaxf(acc[nt][2], acc[nt][3])));
    }
    mx = fmaxf(mx, __shfl_xor(mx, 16));
    mx = fmaxf(mx, __shfl_xor(mx, 32));
    float sm = 0.f;
    #pragma unroll
    for (int nt = 0; nt < 16; ++nt){
      #pragma unroll
      for (int r = 0; r < 4; ++r){
        float e = __expf(acc[nt][r] - mx);
        acc[nt][r] = e; sm += e;
      }
    }
    sm += __shfl_xor(sm, 16);
    sm += __shfl_xor(sm, 32);
    float inv = 1.f / sm;
    #pragma unroll
    for (int nt = 0; nt < 16; ++nt){
      #pragma unroll
      for (int r = 0; r < 4; ++r){
        float p = acc[nt][r] * inv;
        acc[nt][r] = p;
        am[nt][r] += 0.25f * p;
      }
    }
    // ---- ctx = P @ V : in-lane A packs; lane-contiguous V ds_reads ----
    f32x4 oc[4] = {{0,0,0,0},{0,0,0,0},{0,0,0,0},{0,0,0,0}};
    #pragma unroll
    for (int kk = 0; kk < 8; ++kk){
      union { short8 s; unsigned u[4]; } pa;
      pa.u[0] = pk2(acc[2 * kk][0],     acc[2 * kk][1]);
      pa.u[1] = pk2(acc[2 * kk][2],     acc[2 * kk][3]);
      pa.u[2] = pk2(acc[2 * kk + 1][0], acc[2 * kk + 1][1]);
      pa.u[3] = pk2(acc[2 * kk + 1][2], acc[2 * kk + 1][3]);
      #pragma unroll
      for (int n2 = 0; n2 < 4; ++n2){
        short8 vb = *(const short8*)&Vl[(((kk << 2) + n2) << 9) + (lane << 3)];
        oc[n2] = __builtin_amdgcn_mfma_f32_16x16x32_bf16(pa.s, vb, oc[n2], 0, 0, 0);
      }
    }
    // ctx -> standard afrag (for O-GEMM): row m = qw+g*4+r, col = h*64+n2*16+l15
    #pragma unroll
    for (int n2 = 0; n2 < 4; ++n2){
      const int sctx = (h << 1) + (n2 >> 1);
      const int gctx = ((n2 & 1) << 1) + (l15 >> 3);
      const int j = l15 & 7;
      #pragma unroll
      for (int r = 0; r < 4; ++r)
        ctx[(((tileC * 8 + sctx) * 4 + w) * 64 + (gctx << 4) + (g << 2) + r) * 8 + j]
            = f2b(oc[n2][r]);
    }
    __syncthreads();                     // K(h+1) ready; all waves done with Vl
  }

  // ---- am: scatter into swizzled LDS, then 1KB-burst coalesced stores ----
  {
    char* reg = (char*)smem + (w << 14);       // 16KB per wave (f32)
    #pragma unroll
    for (int nt = 0; nt < 16; ++nt){
      unsigned off = ((l15 << 10) + (nt << 6) + (g << 4)) ^ ((l15 & 7) << 4);
      *(f32x4*)(reg + off) = am[nt];
    }
    __syncthreads();
    #pragma unroll
    for (int i2 = 0; i2 < 16; ++i2){
      unsigned fb = (tid << 4) + (i2 << 12);   // flat byte 0..65535
      unsigned rowin = (fb >> 10) & 15;
      f32x4 v = *(const f32x4*)((char*)smem + (fb ^ ((rowin & 7) << 4)));
      unsigned row = fb >> 10;                  // 0..63 within block
      *(f32x4*)&am_out[((size_t)b * 4096 + q0 + row) * 256 + ((fb & 1023) >> 2)] = v;
    }
  }
#undef STG
}

extern "C" void kernel_launch(void* const* d_in, const int* in_sizes, int n_in,
                              void* d_out, int out_size, void* d_ws, size_t ws_size,
                              hipStream_t stream)
{
  const float* node_emb = (const float*)d_in[0];
  const float* cluster  = (const float*)d_in[1];
  const float* cw       = (const float*)d_in[2];
  const float* ln_q_g   = (const float*)d_in[3];
  const float* ln_q_b   = (const float*)d_in[4];
  const float* ln_kv_g  = (const float*)d_in[5];
  const float* ln_kv_b  = (const float*)d_in[6];
  const float* ln_o_g   = (const float*)d_in[7];
  const float* ln_o_b   = (const float*)d_in[8];
  const float* W_q  = (const float*)d_in[9];  const float* b_q  = (const float*)d_in[10];
  const float* W_k  = (const float*)d_in[11]; const float* b_k  = (const float*)d_in[12];
  const float* W_v  = (const float*)d_in[13]; const float* b_v  = (const float*)d_in[14];
  const float* W_o  = (const float*)d_in[15]; const float* b_o  = (const float*)d_in[16];
  const float* W_m1 = (const float*)d_in[17]; const float* b_m1 = (const float*)d_in[18];
  const float* W_m2 = (const float*)d_in[19]; const float* b_m2 = (const float*)d_in[20];

  char* ws = (char*)d_ws;
  short* Wbf   = (short*)ws;                                   // 786,432 B (stage-order)
  short* bufA  = (short*)(ws + 786432);                        // 16.78 MB: afnode -> ctx -> h1
  short* bufB  = (short*)(ws + 786432 + 16777216);             // 16.78 MB: Qaf -> lnx
  short* kvaf  = (short*)(ws + 786432 + 2 * 16777216);         // 1 MB
  short* kfrag = (short*)(ws + 786432 + 2 * 16777216 + 1048576);
  short* vfrag = (short*)(ws + 786432 + 2 * 16777216 + 2 * 1048576);

  float* xbuf = (float*)d_out;            // first half: x, then final out (in-place)
  float* amof = (float*)d_out + 8388608;  // second half: attn_matrix

  hipFuncSetAttribute((const void*)attn_k, hipFuncAttributeMaxDynamicSharedMemorySize, 65536);
  hipFuncSetAttribute((const void*)gemmF<0,0,0,4,0>, hipFuncAttributeMaxDynamicSharedMemorySize, 131072);
  hipFuncSetAttribute((const void*)gemmF<0,0,0,1,0>, hipFuncAttributeMaxDynamicSharedMemorySize, 131072);
  hipFuncSetAttribute((const void*)gemmF<0,0,0,2,0>, hipFuncAttributeMaxDynamicSharedMemorySize, 131072);
  hipFuncSetAttribute((const void*)gemmF<0,1,1,0,1>, hipFuncAttributeMaxDynamicSharedMemorySize, 131072);
  hipFuncSetAttribute((const void*)gemmF<1,0,0,4,0>, hipFuncAttributeMaxDynamicSharedMemorySize, 131072);
  hipFuncSetAttribute((const void*)gemmF<0,1,1,0,0>, hipFuncAttributeMaxDynamicSharedMemorySize, 131072);

  cvt_w<<<1536, 256, 0, stream>>>(W_q, W_k, W_v, W_o, W_m1, W_m2, Wbf);
  // input LayerNorms -> afrag
  lnq_k<<<512, 256, 0, stream>>>(node_emb, ln_q_g, ln_q_b, bufA);
  lnq_k<<<32, 256, 0, stream>>>(cluster, ln_kv_g, ln_kv_b, kvaf);
  // Q projection -> afrag (bufB)
  gemmF<0,0,0,4,0><<<256, 256, 131072, stream>>>(bufA, Wbf, b_q,
      nullptr, nullptr, bufB, nullptr, nullptr, nullptr, 512);
  // K / V projections -> kfrag / vfrag
  gemmF<0,0,0,1,0><<<32, 256, 131072, stream>>>(kvaf, Wbf + 65536, b_k,
      nullptr, nullptr, kfrag, nullptr, nullptr, nullptr, 32);
  gemmF<0,0,0,2,0><<<32, 256, 131072, stream>>>(kvaf, Wbf + 131072, b_v,
      nullptr, nullptr, vfrag, nullptr, nullptr, nullptr, 32);
  // attention (ctx afrag -> bufA, attn_matrix -> d_out 2nd half)
  attn_k<<<dim3(64, 8), 256, 65536, stream>>>(bufB, kfrag, vfrag, cw, bufA, amof);
  // O proj + residual(node_emb) -> x f32 (d_out) + LN(x) afrag (bufB)
  gemmF<0,1,1,0,1><<<256, 256, 131072, stream>>>(bufA, Wbf + 196608, b_o,
      node_emb, xbuf, nullptr, ln_o_g, ln_o_b, bufB, 512);
  // MLP1 + GELU -> h1 afrag (bufA)
  gemmF<1,0,0,4,0><<<256, 256, 131072, stream>>>(bufB, Wbf + 262144, b_m1,
      nullptr, nullptr, bufA, nullptr, nullptr, nullptr, 512);
  // MLP2 + residual(x) -> final out f32 (in-place over x, same-index)
  gemmF<0,1,1,0,0><<<256, 256, 131072, stream>>>(bufA, Wbf + 327680, b_m2,
      xbuf, xbuf, nullptr, nullptr, nullptr, nullptr, 512);
}

// Round 12
// 164.619 us; speedup vs baseline: 1.6339x; 1.6339x over previous
//
#include <hip/hip_runtime.h>
#include <math.h>

typedef __attribute__((ext_vector_type(8))) short short8;
typedef __attribute__((ext_vector_type(4))) float f32x4;
typedef __attribute__((ext_vector_type(2))) unsigned int u32x2;

#define AS1 __attribute__((address_space(1)))
#define AS3 __attribute__((address_space(3)))

__device__ __forceinline__ float b2f(short s){
  return __uint_as_float(((unsigned int)(unsigned short)s) << 16);
}
__device__ __forceinline__ short f2b(float f){
  unsigned int u = __float_as_uint(f);
  u = (u + 0x7fffu + ((u >> 16) & 1u)) >> 16;
  return (short)u;
}
__device__ __forceinline__ unsigned pk2(float lo, float hi){
  return ((unsigned)(unsigned short)f2b(hi) << 16) | (unsigned)(unsigned short)f2b(lo);
}

// ---------------- weight f32 -> bf16, linear stage-order [s][row][g][8] ------
__global__ __launch_bounds__(256) void cvt_w(
    const float* __restrict__ s0, const float* __restrict__ s1,
    const float* __restrict__ s2, const float* __restrict__ s3,
    const float* __restrict__ s4, const float* __restrict__ s5,
    short* __restrict__ dst)
{
  const float* srcs[6] = {s0, s1, s2, s3, s4, s5};
  int i = blockIdx.x * 256 + threadIdx.x;       // 6*65536 total
  int mat = i >> 16, rc = i & 65535;
  int row = rc >> 8, col = rc & 255;
  int d = mat * 65536 + ((col >> 5) << 13) + (row << 5)
        + (((col >> 3) & 3) << 3) + (col & 7);
  dst[d] = f2b(srcs[mat][rc]);
}

// ---------------- LayerNorm f32 -> bf16 afrag writer -------------------------
// Block = 1 tile (64 rows), 256 thr (4 thr/row, 64 cols each).
// afrag: chunk (tile,s,w,lane=g*16+l15) = row w*16+l15, cols s*32+g*8 (16B).
__global__ __launch_bounds__(256) void lnq_k(
    const float* __restrict__ x, const float* __restrict__ g,
    const float* __restrict__ bta, short* __restrict__ af)
{
  const int tile = blockIdx.x, tid = threadIdx.x;
  const int row = tid >> 2, c0 = (tid & 3) << 6;
  const float* src = &x[((size_t)tile * 64 + row) * 256 + c0];
  float vv[64];
  #pragma unroll
  for (int i = 0; i < 16; ++i) *(f32x4*)&vv[4 * i] = *(const f32x4*)&src[4 * i];
  float s1 = 0.f, s2 = 0.f;
  #pragma unroll
  for (int i = 0; i < 64; ++i){ s1 += vv[i]; s2 += vv[i] * vv[i]; }
  s1 += __shfl_xor(s1, 1); s2 += __shfl_xor(s2, 1);
  s1 += __shfl_xor(s1, 2); s2 += __shfl_xor(s2, 2);
  const float mu = s1 * 0.00390625f;
  const float rs = rsqrtf(s2 * 0.00390625f - mu * mu + 1e-5f);
  const int w = row >> 4, l15 = row & 15;
  #pragma unroll
  for (int i = 0; i < 8; ++i){
    const int col0 = c0 + 8 * i;
    f32x4 g0 = *(const f32x4*)&g[col0],   g1 = *(const f32x4*)&g[col0 + 4];
    f32x4 b0 = *(const f32x4*)&bta[col0], b1 = *(const f32x4*)&bta[col0 + 4];
    short8 o;
    #pragma unroll
    for (int j = 0; j < 4; ++j) o[j] = f2b((vv[8 * i + j] - mu) * rs * g0[j] + b0[j]);
    #pragma unroll
    for (int j = 0; j < 4; ++j) o[4 + j] = f2b((vv[8 * i + 4 + j] - mu) * rs * g1[j] + b1[j]);
    const int s = col0 >> 5, gg = (col0 >> 3) & 3;
    *(short8*)&af[((((size_t)tile * 8 + s) * 4 + w) * 64 + gg * 16 + l15) * 8] = o;
  }
}

// ---------------- streaming GEMM, A-afrag in registers, W dbuf in LDS --------
// Block = 1 tile (64 rows x 256 cols), 4 waves, __launch_bounds__(256,3)
// -> 12 waves/CU. A: 8 coalesced 1KB frag loads (afrag layout). W: stage-order,
// 32KB double buffer via global_load_lds, stage s+1 -> MFMA(s) -> barrier.
// Epilogue: GELU / RES f32 residual / OF f32 out / OT: 1 kfrag, 2 vfrag,
// 4 afrag / LNO: row-LN -> afrag outL.
template<int GELU, int RES, int OF, int OT, int LNO>
__global__ __launch_bounds__(256, 3) void gemmS(
    const short* __restrict__ Aaf, const short* __restrict__ Wst,
    const float* __restrict__ bias, const float* __restrict__ resF,
    float* __restrict__ outF, short* __restrict__ outT,
    const float* __restrict__ lng, const float* __restrict__ lnb,
    short* __restrict__ outL)
{
  __shared__ short Ws[2][8192];        // 2 x 16KB k-slice dbuf
  const int tid = threadIdx.x;
  const int tile = blockIdx.x;
  const int w = tid >> 6, lane = tid & 63;
  const int l15 = lane & 15, g = lane >> 4;

  // ---- A fragments (coalesced 1KB per wave-instr) ----
  short8 afr[8];
  #pragma unroll
  for (int s = 0; s < 8; ++s)
    afr[s] = *(const short8*)&Aaf[((((size_t)tile << 3) + s) * 4 + w) * 512 + (lane << 3)];

  // ---- stage W slice 0 ----
  #pragma unroll
  for (int it = 0; it < 4; ++it){
    int c = (it << 8) + tid;
    __builtin_amdgcn_global_load_lds((const AS1 void*)(Wst + ((size_t)c << 3)),
                                     (AS3 void*)(&Ws[0][0] + (c << 3)), 16, 0, 0);
  }
  __syncthreads();

  f32x4 acc[16];
  #pragma unroll
  for (int nt = 0; nt < 16; ++nt) acc[nt] = {0.f, 0.f, 0.f, 0.f};

  int cur = 0;
  for (int s = 0; s < 8; ++s){
    if (s < 7){
      #pragma unroll
      for (int it = 0; it < 4; ++it){
        int c = (it << 8) + tid;
        __builtin_amdgcn_global_load_lds(
            (const AS1 void*)(Wst + (((size_t)(s + 1)) << 13) + ((size_t)c << 3)),
            (AS3 void*)(&Ws[cur ^ 1][0] + (c << 3)), 16, 0, 0);
      }
    }
    const short8 af = afr[s];
    #pragma unroll
    for (int nt = 0; nt < 16; ++nt){
      short8 bf = *(const short8*)&Ws[cur][((nt << 4) + l15) * 32 + (g << 3)];
      acc[nt] = __builtin_amdgcn_mfma_f32_16x16x32_bf16(af, bf, acc[nt], 0, 0, 0);
    }
    __syncthreads();
    cur ^= 1;
  }

  // ---- epilogue ----
  const int m0 = tile << 6;
  const int row_l = (w << 4) + (g << 2);
  #pragma unroll
  for (int nt = 0; nt < 16; ++nt){
    const int col = (nt << 4) + l15;
    const float bv = bias[col];
    #pragma unroll
    for (int r = 0; r < 4; ++r){
      const int m = m0 + row_l + r;
      const size_t idx = (size_t)m * 256 + col;
      float v = acc[nt][r] + bv;
      if (GELU) v = 0.5f * v * (1.0f + erff(v * 0.70710678118f));
      if (RES) v += resF[idx];
      if (OF) outF[idx] = v;
      acc[nt][r] = v;
      if (OT == 1){   // kfrag: [b][h][nt16][half][g][l15][8]
        const int b_ = m >> 8, kvr = m & 255;
        const int knt = kvr >> 4, kl = kvr & 15;
        const int h = col >> 6, half = (col >> 5) & 1, kg = (col >> 3) & 3, kj = col & 7;
        outT[(((((size_t)(b_ * 4 + h) * 16 + knt) * 2 + half) * 4 + kg) * 16 + kl) * 8 + kj] = f2b(v);
      }
      if (OT == 2){   // vfrag: [b][h][kk][n2][g][l15][8]
        const int b_ = m >> 8, kvj = m & 255;
        const int jp = (kvj & ~31) | (((kvj >> 2) & 3) << 3) | (((kvj >> 4) & 1) << 2) | (kvj & 3);
        const int h = col >> 6, dp = col & 63;
        const int kk = jp >> 5, vg = (jp >> 3) & 3, vj = jp & 7;
        const int vn2 = dp >> 4, vl = dp & 15;
        outT[(((((size_t)(b_ * 4 + h) * 8 + kk) * 4 + vn2) * 4 + vg) * 16 + vl) * 8 + vj] = f2b(v);
      }
      if (OT == 4){   // standard afrag
        outT[((((size_t)tile * 8 + (col >> 5)) * 4 + w) * 64
              + (((col >> 3) & 3) << 4) + (g << 2) + r) * 8 + (col & 7)] = f2b(v);
      }
    }
  }
  if (LNO){
    #pragma unroll
    for (int r = 0; r < 4; ++r){
      float s1 = 0.f, s2 = 0.f;
      #pragma unroll
      for (int nt = 0; nt < 16; ++nt){ float v = acc[nt][r]; s1 += v; s2 += v * v; }
      #pragma unroll
      for (int off = 1; off < 16; off <<= 1){ s1 += __shfl_xor(s1, off); s2 += __shfl_xor(s2, off); }
      const float mu = s1 * 0.00390625f;
      const float rs = rsqrtf(s2 * 0.00390625f - mu * mu + 1e-5f);
      #pragma unroll
      for (int nt = 0; nt < 16; ++nt){
        const int col = (nt << 4) + l15;
        float lv = (acc[nt][r] - mu) * rs * lng[col] + lnb[col];
        outL[((((size_t)tile * 8 + (col >> 5)) * 4 + w) * 64
              + (((col >> 3) & 3) << 4) + (g << 2) + r) * 8 + (col & 7)] = f2b(lv);
      }
    }
  }
}

// ---------------- fused MFMA attention (r10 structure, unchanged) ------------
// Block: 256 thr = 4 waves x 16 q-rows; grid 64x8 = 512 blocks (2/CU).
// LDS 64KB: K | V split-phase staging. cw: 1KB bursts -> swizzled LDS bounce
// -> packed regs. Q from standard afrag. ctx written in afrag order for O.
// am via LDS bounce -> 1KB-burst stores.
__global__ __launch_bounds__(256, 2) void attn_k(
    const short* __restrict__ Qf, const short* __restrict__ Kf,
    const short* __restrict__ Vf, const float* __restrict__ cw,
    short* __restrict__ ctx, float* __restrict__ am_out)
{
  extern __shared__ __align__(16) short smem[];   // 32768 shorts = 64KB
  short* Kl = smem;
  short* Vl = smem + 16384;
  const int b = blockIdx.y;
  const int q0 = blockIdx.x << 6;
  const int tid = threadIdx.x;
  const int w = tid >> 6, lane = tid & 63;
  const int l15 = lane & 15, g = lane >> 4;
  const size_t qw = (size_t)b * 4096 + q0 + (w << 4);   // wave's first q row
  const size_t qblk = qw >> 4;
  const size_t tileQ = qblk >> 2;
  const int wQ = (int)(qblk & 3);
  const size_t tileC = (size_t)b * 64 + blockIdx.x;     // ctx afrag tile

#define STG(dst_, src_) do{ _Pragma("unroll")                                        \
  for (int it_ = 0; it_ < 8; ++it_){ int c_ = (it_ << 8) + tid;                      \
    __builtin_amdgcn_global_load_lds((const AS1 void*)((src_) + (c_ << 3)),          \
                                     (AS3 void*)((dst_) + (c_ << 3)), 16, 0, 0); } }while(0)

  // ---- cw: full-row coalesced load -> swizzled LDS -> scattered reg read ----
  unsigned cwp[16][2];
  f32x4 am[16];
  {
    char* reg = (char*)smem + (w << 13);       // 8KB per wave
    #pragma unroll
    for (int j = 0; j < 16; ++j){
      f32x4 v = *(const f32x4*)&cw[(qw + j) * 256 + (lane << 2)];  // 1KB burst/instr
      u32x2 d = { pk2(v[0], v[1]), pk2(v[2], v[3]) };
      unsigned off = ((j << 9) + (lane << 3)) ^ ((j & 7) << 4);
      *(u32x2*)(reg + off) = d;
    }
    __syncthreads();
    #pragma unroll
    for (int nt = 0; nt < 16; ++nt){
      unsigned base = ((l15 << 9) + (nt << 5) + (g << 3)) ^ ((l15 & 7) << 4);
      cwp[nt][0] = *(const unsigned*)(reg + base);
      cwp[nt][1] = *(const unsigned*)(reg + base + 4);
      am[nt] = {0.f, 0.f, 0.f, 0.f};
    }
    __syncthreads();
  }

  STG(Kl, Kf + ((size_t)(b * 4) << 14));
  __syncthreads();                       // K(0) staged

  for (int h = 0; h < 4; ++h){
    STG(Vl, Vf + ((size_t)(b * 4 + h) << 14));          // V(h) under QK
    short8 qf0 = *(const short8*)&Qf[(((tileQ * 8 + (h << 1)) * 4 + wQ) * 64 + lane) * 8];
    short8 qf1 = *(const short8*)&Qf[(((tileQ * 8 + (h << 1) + 1) * 4 + wQ) * 64 + lane) * 8];

    // ---- scores: swapped operands, lane-contiguous ds_read_b128 ----
    f32x4 acc[16];
    #pragma unroll
    for (int nt = 0; nt < 16; ++nt) acc[nt] = {0.f, 0.f, 0.f, 0.f};
    #pragma unroll
    for (int nt = 0; nt < 16; ++nt){
      short8 kf0 = *(const short8*)&Kl[(nt << 10) + (lane << 3)];
      acc[nt] = __builtin_amdgcn_mfma_f32_16x16x32_bf16(kf0, qf0, acc[nt], 0, 0, 0);
      short8 kf1 = *(const short8*)&Kl[(nt << 10) + 512 + (lane << 3)];
      acc[nt] = __builtin_amdgcn_mfma_f32_16x16x32_bf16(kf1, qf1, acc[nt], 0, 0, 0);
    }
    __syncthreads();                     // V(h) ready; all waves done with Kl
    if (h < 3) STG(Kl, Kf + ((size_t)(b * 4 + h + 1) << 14));   // K(h+1) under softmax+PV

    // ---- softmax, fully in-lane (row q = l15; partners at lane^16, lane^32) ----
    float mx = -3.4e38f;
    #pragma unroll
    for (int nt = 0; nt < 16; ++nt){
      float c0 = __uint_as_float(cwp[nt][0] << 16);
      float c1 = __uint_as_float(cwp[nt][0] & 0xffff0000u);
      float c2 = __uint_as_float(cwp[nt][1] << 16);
      float c3 = __uint_as_float(cwp[nt][1] & 0xffff0000u);
      acc[nt][0] = acc[nt][0] * 0.125f + c0;
      acc[nt][1] = acc[nt][1] * 0.125f + c1;
      acc[nt][2] = acc[nt][2] * 0.125f + c2;
      acc[nt][3] = acc[nt][3] * 0.125f + c3;
      mx = fmaxf(mx, fmaxf(fmaxf(acc[nt][0], acc[nt][1]), fmaxf(acc[nt][2], acc[nt][3])));
    }
    mx = fmaxf(mx, __shfl_xor(mx, 16));
    mx = fmaxf(mx, __shfl_xor(mx, 32));
    float sm = 0.f;
    #pragma unroll
    for (int nt = 0; nt < 16; ++nt){
      #pragma unroll
      for (int r = 0; r < 4; ++r){
        float e = __expf(acc[nt][r] - mx);
        acc[nt][r] = e; sm += e;
      }
    }
    sm += __shfl_xor(sm, 16);
    sm += __shfl_xor(sm, 32);
    float inv = 1.f / sm;
    #pragma unroll
    for (int nt = 0; nt < 16; ++nt){
      #pragma unroll
      for (int r = 0; r < 4; ++r){
        float p = acc[nt][r] * inv;
        acc[nt][r] = p;
        am[nt][r] += 0.25f * p;
      }
    }
    // ---- ctx = P @ V : in-lane A packs; lane-contiguous V ds_reads ----
    f32x4 oc[4] = {{0,0,0,0},{0,0,0,0},{0,0,0,0},{0,0,0,0}};
    #pragma unroll
    for (int kk = 0; kk < 8; ++kk){
      union { short8 s; unsigned u[4]; } pa;
      pa.u[0] = pk2(acc[2 * kk][0],     acc[2 * kk][1]);
      pa.u[1] = pk2(acc[2 * kk][2],     acc[2 * kk][3]);
      pa.u[2] = pk2(acc[2 * kk + 1][0], acc[2 * kk + 1][1]);
      pa.u[3] = pk2(acc[2 * kk + 1][2], acc[2 * kk + 1][3]);
      #pragma unroll
      for (int n2 = 0; n2 < 4; ++n2){
        short8 vb = *(const short8*)&Vl[(((kk << 2) + n2) << 9) + (lane << 3)];
        oc[n2] = __builtin_amdgcn_mfma_f32_16x16x32_bf16(pa.s, vb, oc[n2], 0, 0, 0);
      }
    }
    // ctx -> standard afrag (for O-GEMM): row m = qw+g*4+r, col = h*64+n2*16+l15
    #pragma unroll
    for (int n2 = 0; n2 < 4; ++n2){
      const int sctx = (h << 1) + (n2 >> 1);
      const int gctx = ((n2 & 1) << 1) + (l15 >> 3);
      const int j = l15 & 7;
      #pragma unroll
      for (int r = 0; r < 4; ++r)
        ctx[(((tileC * 8 + sctx) * 4 + w) * 64 + (gctx << 4) + (g << 2) + r) * 8 + j]
            = f2b(oc[n2][r]);
    }
    __syncthreads();                     // K(h+1) ready; all waves done with Vl
  }

  // ---- am: scatter into swizzled LDS, then 1KB-burst coalesced stores ----
  {
    char* reg = (char*)smem + (w << 14);       // 16KB per wave (f32)
    #pragma unroll
    for (int nt = 0; nt < 16; ++nt){
      unsigned off = ((l15 << 10) + (nt << 6) + (g << 4)) ^ ((l15 & 7) << 4);
      *(f32x4*)(reg + off) = am[nt];
    }
    __syncthreads();
    #pragma unroll
    for (int i2 = 0; i2 < 16; ++i2){
      unsigned fb = (tid << 4) + (i2 << 12);   // flat byte 0..65535
      unsigned rowin = (fb >> 10) & 15;
      f32x4 v = *(const f32x4*)((char*)smem + (fb ^ ((rowin & 7) << 4)));
      unsigned row = fb >> 10;                  // 0..63 within block
      *(f32x4*)&am_out[((size_t)b * 4096 + q0 + row) * 256 + ((fb & 1023) >> 2)] = v;
    }
  }
#undef STG
}

extern "C" void kernel_launch(void* const* d_in, const int* in_sizes, int n_in,
                              void* d_out, int out_size, void* d_ws, size_t ws_size,
                              hipStream_t stream)
{
  const float* node_emb = (const float*)d_in[0];
  const float* cluster  = (const float*)d_in[1];
  const float* cw       = (const float*)d_in[2];
  const float* ln_q_g   = (const float*)d_in[3];
  const float* ln_q_b   = (const float*)d_in[4];
  const float* ln_kv_g  = (const float*)d_in[5];
  const float* ln_kv_b  = (const float*)d_in[6];
  const float* ln_o_g   = (const float*)d_in[7];
  const float* ln_o_b   = (const float*)d_in[8];
  const float* W_q  = (const float*)d_in[9];  const float* b_q  = (const float*)d_in[10];
  const float* W_k  = (const float*)d_in[11]; const float* b_k  = (const float*)d_in[12];
  const float* W_v  = (const float*)d_in[13]; const float* b_v  = (const float*)d_in[14];
  const float* W_o  = (const float*)d_in[15]; const float* b_o  = (const float*)d_in[16];
  const float* W_m1 = (const float*)d_in[17]; const float* b_m1 = (const float*)d_in[18];
  const float* W_m2 = (const float*)d_in[19]; const float* b_m2 = (const float*)d_in[20];

  char* ws = (char*)d_ws;
  short* Wbf   = (short*)ws;                                   // 786,432 B (stage-order)
  short* bufA  = (short*)(ws + 786432);                        // 16.78 MB: afnode -> ctx -> h1
  short* bufB  = (short*)(ws + 786432 + 16777216);             // 16.78 MB: Qaf -> lnx
  short* kvaf  = (short*)(ws + 786432 + 2 * 16777216);         // 1 MB
  short* kfrag = (short*)(ws + 786432 + 2 * 16777216 + 1048576);
  short* vfrag = (short*)(ws + 786432 + 2 * 16777216 + 2 * 1048576);

  float* xbuf = (float*)d_out;            // first half: x, then final out (in-place)
  float* amof = (float*)d_out + 8388608;  // second half: attn_matrix

  hipFuncSetAttribute((const void*)attn_k, hipFuncAttributeMaxDynamicSharedMemorySize, 65536);

  cvt_w<<<1536, 256, 0, stream>>>(W_q, W_k, W_v, W_o, W_m1, W_m2, Wbf);
  // input LayerNorms -> afrag
  lnq_k<<<512, 256, 0, stream>>>(node_emb, ln_q_g, ln_q_b, bufA);
  lnq_k<<<32, 256, 0, stream>>>(cluster, ln_kv_g, ln_kv_b, kvaf);
  // Q projection -> afrag (bufB)
  gemmS<0,0,0,4,0><<<512, 256, 0, stream>>>(bufA, Wbf, b_q,
      nullptr, nullptr, bufB, nullptr, nullptr, nullptr);
  // K / V projections -> kfrag / vfrag
  gemmS<0,0,0,1,0><<<32, 256, 0, stream>>>(kvaf, Wbf + 65536, b_k,
      nullptr, nullptr, kfrag, nullptr, nullptr, nullptr);
  gemmS<0,0,0,2,0><<<32, 256, 0, stream>>>(kvaf, Wbf + 131072, b_v,
      nullptr, nullptr, vfrag, nullptr, nullptr, nullptr);
  // attention (ctx afrag -> bufA, attn_matrix -> d_out 2nd half)
  attn_k<<<dim3(64, 8), 256, 65536, stream>>>(bufB, kfrag, vfrag, cw, bufA, amof);
  // O proj + residual(node_emb) -> x f32 (d_out) + LN(x) afrag (bufB)
  gemmS<0,1,1,0,1><<<512, 256, 0, stream>>>(bufA, Wbf + 196608, b_o,
      node_emb, xbuf, nullptr, ln_o_g, ln_o_b, bufB);
  // MLP1 + GELU -> h1 afrag (bufA)
  gemmS<1,0,0,4,0><<<512, 256, 0, stream>>>(bufB, Wbf + 262144, b_m1,
      nullptr, nullptr, bufA, nullptr, nullptr, nullptr);
  // MLP2 + residual(x) -> final out f32 (in-place over x, same-index)
  gemmS<0,1,1,0,0><<<512, 256, 0, stream>>>(bufA, Wbf + 327680, b_m2,
      xbuf, xbuf, nullptr, nullptr, nullptr, nullptr);
}